// Round 11
// baseline (1042.439 us; speedup 1.0000x reference)
//
#include <hip/hip_runtime.h>
#include <hip/hip_bf16.h>

// GAE: h1 = relu(gcn(x,W1,b1)); z = gcn(h1,W2,b2); out = sigmoid(dot(Y[src], z[dst]) + bb)
// where Y = z @ Wb[0]  (bilinear refactor).
// PULL aggregation over on-device CSR; gathered node matrices bf16.
// Round 11: the tail chain (bucket_sort -> agg1 -> gemm2 -> agg2 -> gemmY ->
// decode) is ONE persistent kernel (1024 blocks = 4/CU co-resident via
// 35KB LDS + launch_bounds(256,4)) with agent-scope grid barriers, removing
// 5 dispatch boundaries (~3-5us each). Phase bodies bit-identical to round 10.

#define N_NODES 50000
#define BSH 7
#define BSZ 128
#define NBUCK ((N_NODES + BSZ - 1) / BSZ)   // 391
#define EPB 4096
#define CAP 3072
#define TGRID 1024                          // persistent tail grid (4 blocks/CU)

typedef unsigned int u32;
typedef unsigned short u16;

typedef __attribute__((ext_vector_type(8))) short bf16x8;
typedef __attribute__((ext_vector_type(4))) float f32x4;
union frag_u { bf16x8 f; u32 u[4]; uint4 v; };

__device__ __forceinline__ float bflo(u32 u) { return __uint_as_float(u << 16); }
__device__ __forceinline__ float bfhi(u32 u) { return __uint_as_float(u & 0xffff0000u); }
__device__ __forceinline__ u32 f2bf(float f) {
    u32 b = __float_as_uint(f);
    return (b + 0x7fffu + ((b >> 16) & 1u)) >> 16;
}
__device__ __forceinline__ u32 pack2(float a, float b) { return f2bf(a) | (f2bf(b) << 16); }

// device-scope grid barrier: monotonic counter (zeroed by host memset),
// target = phase * gridDim. ACQ_REL/ACQUIRE at AGENT scope -> L2 wb/inv on gfx950.
__device__ __forceinline__ void gbar_sync(int* bar, int target) {
    __syncthreads();
    if (threadIdx.x == 0) {
        __hip_atomic_fetch_add(bar, 1, __ATOMIC_ACQ_REL, __HIP_MEMORY_SCOPE_AGENT);
        while (__hip_atomic_load(bar, __ATOMIC_ACQUIRE, __HIP_MEMORY_SCOPE_AGENT) < target)
            __builtin_amdgcn_s_sleep(2);
    }
    __syncthreads();
}

// ================= fused: gemm1 (blocks < gblk) | bucket_scatter (rest) =================
__global__ __launch_bounds__(256) void gemm1_scatter(
        const float* __restrict__ X, const float* __restrict__ W,
        u16* __restrict__ O, int n_rows, int gblk,
        const int* __restrict__ src, const int* __restrict__ dst,
        int* __restrict__ bcur, u32* __restrict__ pair, int E) {
    constexpr int K = 128, NOUT = 128;
    constexpr int KP = K + 8;
    constexpr int NT = NOUT / 16;
    constexpr int KS = K / 32;
    __shared__ __align__(16) char smem[NOUT * KP * 2 * sizeof(u16)];
    int t = threadIdx.x;

    if ((int)blockIdx.x < gblk) {
        u16* Wt_hi = (u16*)smem;
        u16* Wt_lo = Wt_hi + NOUT * KP;
        for (int i4 = t; i4 < K * NOUT / 4; i4 += 256) {
            int k = (i4 * 4) / NOUT;
            int n0 = (i4 * 4) % NOUT;
            float4 w4 = *(const float4*)&W[(size_t)k * NOUT + n0];
            float wv[4] = {w4.x, w4.y, w4.z, w4.w};
#pragma unroll
            for (int q = 0; q < 4; q++) {
                u32 hi = f2bf(wv[q]);
                u32 lo = f2bf(wv[q] - bflo(hi));
                Wt_hi[(n0 + q) * KP + k] = (u16)hi;
                Wt_lo[(n0 + q) * KP + k] = (u16)lo;
            }
        }
        __syncthreads();

        int wave = t >> 6;
        int lane = t & 63;
        int m16 = lane & 15;
        int quad = lane >> 4;
        int row0 = blockIdx.x * 128 + wave * 32;

        f32x4 acc[2][NT] = {};
        for (int ks = 0; ks < KS; ks++) {
            frag_u a_hi[2], a_lo[2];
#pragma unroll
            for (int mt = 0; mt < 2; mt++) {
                int row = row0 + mt * 16 + m16;
                row = row < n_rows ? row : n_rows - 1;
                const float* Xp = X + (size_t)row * K + ks * 32 + quad * 8;
                float4 x0 = *(const float4*)Xp;
                float4 x1 = *(const float4*)(Xp + 4);
                float xv[8] = {x0.x, x0.y, x0.z, x0.w, x1.x, x1.y, x1.z, x1.w};
#pragma unroll
                for (int p = 0; p < 4; p++) {
                    u32 h0 = f2bf(xv[2 * p]), h1 = f2bf(xv[2 * p + 1]);
                    a_hi[mt].u[p] = h0 | (h1 << 16);
                    a_lo[mt].u[p] = pack2(xv[2 * p] - bflo(h0), xv[2 * p + 1] - bflo(h1));
                }
            }
#pragma unroll
            for (int nt = 0; nt < NT; nt++) {
                int n = nt * 16 + m16;
                frag_u b_hi, b_lo;
                b_hi.v = *(const uint4*)&Wt_hi[n * KP + ks * 32 + quad * 8];
                b_lo.v = *(const uint4*)&Wt_lo[n * KP + ks * 32 + quad * 8];
#pragma unroll
                for (int mt = 0; mt < 2; mt++) {
                    acc[mt][nt] = __builtin_amdgcn_mfma_f32_16x16x32_bf16(a_hi[mt].f, b_hi.f, acc[mt][nt], 0, 0, 0);
                    acc[mt][nt] = __builtin_amdgcn_mfma_f32_16x16x32_bf16(a_hi[mt].f, b_lo.f, acc[mt][nt], 0, 0, 0);
                    acc[mt][nt] = __builtin_amdgcn_mfma_f32_16x16x32_bf16(a_lo[mt].f, b_hi.f, acc[mt][nt], 0, 0, 0);
                }
            }
        }
#pragma unroll
        for (int mt = 0; mt < 2; mt++)
#pragma unroll
            for (int nt = 0; nt < NT; nt++)
#pragma unroll
                for (int r = 0; r < 4; r++) {
                    int row = row0 + mt * 16 + quad * 4 + r;
                    if (row < n_rows)
                        O[(size_t)row * NOUT + nt * 16 + m16] = (u16)f2bf(acc[mt][nt][r]);
                }
    } else {
        int* hist = (int*)smem;
        for (int i = t; i < NBUCK; i += 256) hist[i] = 0;
        __syncthreads();
        int base = ((int)blockIdx.x - gblk) * EPB;
        int s_[16], d_[16];
#pragma unroll
        for (int it = 0; it < 16; it++) {
            int e = base + it * 256 + t;
            if (e < E) {
                s_[it] = src[e];
                d_[it] = dst[e];
                atomicAdd(&hist[d_[it] >> BSH], 1);
            } else {
                d_[it] = -1;
            }
        }
        __syncthreads();
        for (int b = t; b < NBUCK; b += 256) {
            int c = hist[b];
            hist[b] = c ? (b * CAP + atomicAdd(&bcur[b], c)) : 0;
        }
        __syncthreads();
#pragma unroll
        for (int it = 0; it < 16; it++) {
            if (d_[it] >= 0) {
                int b = d_[it] >> BSH;
                int off = atomicAdd(&hist[b], 1);
                pair[off] = (u32)s_[it] | ((u32)(d_[it] & (BSZ - 1)) << 16);
            }
        }
    }
}

// ---------------- device fn: agg work-item (node,part), bf16 in/out ----------------
template <int C, bool RELU>
__device__ __forceinline__ void agg_item(size_t wi, const u16* __restrict__ H,
                                         const int* __restrict__ row_ptr,
                                         const int* __restrict__ col,
                                         const float* __restrict__ dinv,
                                         const float* __restrict__ inv,
                                         const float* __restrict__ b,
                                         u16* __restrict__ O) {
    constexpr int TPN = C / 8;
    const uint4* Hv = (const uint4*)H;
    int node = (int)(wi / TPN);
    int part = (int)(wi % TPN);
    int c8 = part * 8;
    float dn = dinv[node];
    float iv = inv[node];
    float acc[8];
    {
        uint4 h = Hv[(size_t)node * TPN + part];
        acc[0] = bflo(h.x) * iv + b[c8 + 0];
        acc[1] = bfhi(h.x) * iv + b[c8 + 1];
        acc[2] = bflo(h.y) * iv + b[c8 + 2];
        acc[3] = bfhi(h.y) * iv + b[c8 + 3];
        acc[4] = bflo(h.z) * iv + b[c8 + 4];
        acc[5] = bfhi(h.z) * iv + b[c8 + 5];
        acc[6] = bflo(h.w) * iv + b[c8 + 6];
        acc[7] = bfhi(h.w) * iv + b[c8 + 7];
    }
    int j = row_ptr[node];
    int end = row_ptr[node + 1];
    for (; j + 3 < end; j += 4) {
        int s0 = col[j], s1 = col[j + 1], s2 = col[j + 2], s3 = col[j + 3];
        float n0 = dn * dinv[s0], n1 = dn * dinv[s1];
        float n2 = dn * dinv[s2], n3 = dn * dinv[s3];
        uint4 v0 = Hv[(size_t)s0 * TPN + part];
        uint4 v1 = Hv[(size_t)s1 * TPN + part];
        uint4 v2 = Hv[(size_t)s2 * TPN + part];
        uint4 v3 = Hv[(size_t)s3 * TPN + part];
        acc[0] += bflo(v0.x) * n0 + bflo(v1.x) * n1 + bflo(v2.x) * n2 + bflo(v3.x) * n3;
        acc[1] += bfhi(v0.x) * n0 + bfhi(v1.x) * n1 + bfhi(v2.x) * n2 + bfhi(v3.x) * n3;
        acc[2] += bflo(v0.y) * n0 + bflo(v1.y) * n1 + bflo(v2.y) * n2 + bflo(v3.y) * n3;
        acc[3] += bfhi(v0.y) * n0 + bfhi(v1.y) * n1 + bfhi(v2.y) * n2 + bfhi(v3.y) * n3;
        acc[4] += bflo(v0.z) * n0 + bflo(v1.z) * n1 + bflo(v2.z) * n2 + bflo(v3.z) * n3;
        acc[5] += bfhi(v0.z) * n0 + bfhi(v1.z) * n1 + bfhi(v2.z) * n2 + bfhi(v3.z) * n3;
        acc[6] += bflo(v0.w) * n0 + bflo(v1.w) * n1 + bflo(v2.w) * n2 + bflo(v3.w) * n3;
        acc[7] += bfhi(v0.w) * n0 + bfhi(v1.w) * n1 + bfhi(v2.w) * n2 + bfhi(v3.w) * n3;
    }
    for (; j < end; j++) {
        int s = col[j];
        float nm = dn * dinv[s];
        uint4 v = Hv[(size_t)s * TPN + part];
        acc[0] += bflo(v.x) * nm; acc[1] += bfhi(v.x) * nm;
        acc[2] += bflo(v.y) * nm; acc[3] += bfhi(v.y) * nm;
        acc[4] += bflo(v.z) * nm; acc[5] += bfhi(v.z) * nm;
        acc[6] += bflo(v.w) * nm; acc[7] += bfhi(v.w) * nm;
    }
    if (RELU) {
#pragma unroll
        for (int i = 0; i < 8; i++) acc[i] = fmaxf(acc[i], 0.f);
    }
    uint4 o;
    o.x = pack2(acc[0], acc[1]);
    o.y = pack2(acc[2], acc[3]);
    o.z = pack2(acc[4], acc[5]);
    o.w = pack2(acc[6], acc[7]);
    ((uint4*)O)[(size_t)node * TPN + part] = o;
}

// ---------------- device fn: one 128-row MFMA tile, bf16 A, f32 W (split hi/lo) --------
template <int K, int NOUT>
__device__ void gemm_tile_bf(const u16* __restrict__ Xv, const float* __restrict__ W,
                             u16* __restrict__ O, int n_rows, int tile,
                             u16* Wt_hi, u16* Wt_lo) {
    constexpr int KP = K + 8;
    constexpr int NT = NOUT / 16;
    constexpr int KS = K / 32;
    int t = threadIdx.x;
    for (int i4 = t; i4 < K * NOUT / 4; i4 += 256) {
        int k = (i4 * 4) / NOUT;
        int n0 = (i4 * 4) % NOUT;
        float4 w4 = *(const float4*)&W[(size_t)k * NOUT + n0];
        float wv[4] = {w4.x, w4.y, w4.z, w4.w};
#pragma unroll
        for (int q = 0; q < 4; q++) {
            u32 hi = f2bf(wv[q]);
            u32 lo = f2bf(wv[q] - bflo(hi));
            Wt_hi[(n0 + q) * KP + k] = (u16)hi;
            Wt_lo[(n0 + q) * KP + k] = (u16)lo;
        }
    }
    __syncthreads();

    int wave = t >> 6;
    int lane = t & 63;
    int m16 = lane & 15;
    int quad = lane >> 4;
    int row0 = tile * 128 + wave * 32;

    f32x4 acc[2][NT] = {};
    for (int ks = 0; ks < KS; ks++) {
        frag_u a_hi[2];
#pragma unroll
        for (int mt = 0; mt < 2; mt++) {
            int row = row0 + mt * 16 + m16;
            row = row < n_rows ? row : n_rows - 1;
            a_hi[mt].v = *(const uint4*)(Xv + (size_t)row * K + ks * 32 + quad * 8);
        }
#pragma unroll
        for (int nt = 0; nt < NT; nt++) {
            int n = nt * 16 + m16;
            frag_u b_hi, b_lo;
            b_hi.v = *(const uint4*)&Wt_hi[n * KP + ks * 32 + quad * 8];
            b_lo.v = *(const uint4*)&Wt_lo[n * KP + ks * 32 + quad * 8];
#pragma unroll
            for (int mt = 0; mt < 2; mt++) {
                acc[mt][nt] = __builtin_amdgcn_mfma_f32_16x16x32_bf16(a_hi[mt].f, b_hi.f, acc[mt][nt], 0, 0, 0);
                acc[mt][nt] = __builtin_amdgcn_mfma_f32_16x16x32_bf16(a_hi[mt].f, b_lo.f, acc[mt][nt], 0, 0, 0);
            }
        }
    }
#pragma unroll
    for (int mt = 0; mt < 2; mt++)
#pragma unroll
        for (int nt = 0; nt < NT; nt++)
#pragma unroll
            for (int r = 0; r < 4; r++) {
                int row = row0 + mt * 16 + quad * 4 + r;
                if (row < n_rows)
                    O[(size_t)row * NOUT + nt * 16 + m16] = (u16)f2bf(acc[mt][nt][r]);
            }
}

// ================= persistent tail: sort | agg1 | gemm2 | agg2 | gemmY | decode ==========
__global__ __launch_bounds__(256, 4) void tail_fused(
        const u32* __restrict__ pair, int* __restrict__ bcur,
        int* __restrict__ row_ptr, int* __restrict__ col,
        float* __restrict__ dinv, float* __restrict__ inv,
        const u16* __restrict__ H1, u16* __restrict__ h1,
        const float* __restrict__ b1, const float* __restrict__ W2,
        u16* __restrict__ H2, const float* __restrict__ b2,
        u16* __restrict__ Z, const float* __restrict__ Wb,
        u16* __restrict__ Y, const float* __restrict__ bb,
        const int* __restrict__ src, const int* __restrict__ dst,
        float* __restrict__ out, int n, int E, int* __restrict__ gbar) {
    // LDS union: gemm2 needs 64*136*2 u16 = 34816 B (max)
    __shared__ __align__(16) char smem[64 * 136 * 2 * sizeof(u16)];
    int t = threadIdx.x;
    const int nb = (int)gridDim.x;
    const size_t gid = (size_t)blockIdx.x * 256 + t;
    const size_t stride = (size_t)nb * 256;

    // ---- phase 1: bucket_sort (blocks < NBUCK) ----
    if ((int)blockIdx.x < NBUCK) {
        int* ssum = (int*)smem;       // 256
        int* cnt = ssum + 256;        // 128
        int* scn = cnt + BSZ;         // 128
        int* cur = scn + BSZ;         // 128
        int base = blockIdx.x << BSH;
        int nn = min(BSZ, n - base);
        int accp = 0;
        for (int i = t; i < (int)blockIdx.x; i += 256) accp += bcur[i];
        ssum[t] = accp;
        __syncthreads();
        for (int s = 128; s > 0; s >>= 1) {
            if (t < s) ssum[t] += ssum[t + s];
            __syncthreads();
        }
        int b0 = ssum[0];
        int cntE = bcur[blockIdx.x];
        int p0 = blockIdx.x * CAP;
        if (t < BSZ) cnt[t] = 0;
        __syncthreads();
        for (int j = t; j < cntE; j += 256)
            atomicAdd(&cnt[pair[p0 + j] >> 16], 1);
        __syncthreads();
        if (t < BSZ) scn[t] = cnt[t];
        __syncthreads();
        for (int off = 1; off < BSZ; off <<= 1) {
            int a = (t < BSZ && t >= off) ? scn[t - off] : 0;
            __syncthreads();
            if (t < BSZ) scn[t] += a;
            __syncthreads();
        }
        if (t < nn) {
            int excl = b0 + scn[t] - cnt[t];
            row_ptr[base + t] = excl;
            cur[t] = excl;
            float d = (float)cnt[t] + 1.0f;
            dinv[base + t] = rsqrtf(d);
            inv[base + t] = 1.0f / d;
        }
        if (t == 0 && (int)blockIdx.x == NBUCK - 1) row_ptr[n] = E;
        __syncthreads();
        for (int j = t; j < cntE; j += 256) {
            u32 p = pair[p0 + j];
            int ln = (int)(p >> 16);
            int pos = atomicAdd(&cur[ln], 1);
            col[pos] = (int)(p & 0xffffu);
        }
    }
    gbar_sync(gbar, nb * 1);

    // ---- phase 2: agg1 (C=128, relu) ----
    for (size_t w = gid; w < (size_t)n * 16; w += stride)
        agg_item<128, true>(w, H1, row_ptr, col, dinv, inv, b1, h1);
    gbar_sync(gbar, nb * 2);

    // ---- phase 3: gemm2 H2 = h1 @ W2 ----
    {
        int ntile = (n + 127) / 128;
        u16* Wt_hi = (u16*)smem;
        u16* Wt_lo = Wt_hi + 64 * (128 + 8);
        if ((int)blockIdx.x < ntile)
            gemm_tile_bf<128, 64>(h1, W2, H2, n, blockIdx.x, Wt_hi, Wt_lo);
    }
    gbar_sync(gbar, nb * 3);

    // ---- phase 4: agg2 (C=64) ----
    for (size_t w = gid; w < (size_t)n * 8; w += stride)
        agg_item<64, false>(w, H2, row_ptr, col, dinv, inv, b2, Z);
    gbar_sync(gbar, nb * 4);

    // ---- phase 5: gemmY Y = Z @ Wb ----
    {
        int ntile = (n + 127) / 128;
        u16* Wt_hi = (u16*)smem;
        u16* Wt_lo = Wt_hi + 64 * (64 + 8);
        if ((int)blockIdx.x < ntile)
            gemm_tile_bf<64, 64>(Z, Wb, Y, n, blockIdx.x, Wt_hi, Wt_lo);
    }
    gbar_sync(gbar, nb * 5);

    // ---- phase 6: decode ----
    {
        const uint4* Yv = (const uint4*)Y;
        const uint4* Zv = (const uint4*)Z;
        float bbv = bb[0];
        for (size_t w = gid; w < (size_t)E * 8; w += stride) {
            int e = (int)(w / 8);
            int lane = (int)(w % 8);
            int s = src[e], d = dst[e];
            uint4 y = Yv[(size_t)s * 8 + lane];
            uint4 z = Zv[(size_t)d * 8 + lane];
            float p = bflo(y.x) * bflo(z.x) + bfhi(y.x) * bfhi(z.x)
                    + bflo(y.y) * bflo(z.y) + bfhi(y.y) * bfhi(z.y)
                    + bflo(y.z) * bflo(z.z) + bfhi(y.z) * bfhi(z.z)
                    + bflo(y.w) * bflo(z.w) + bfhi(y.w) * bfhi(z.w);
            p += __shfl_down(p, 4, 8);
            p += __shfl_down(p, 2, 8);
            p += __shfl_down(p, 1, 8);
            if (lane == 0) out[e] = 1.0f / (1.0f + expf(-(p + bbv)));
        }
    }
}

extern "C" void kernel_launch(void* const* d_in, const int* in_sizes, int n_in,
                              void* d_out, int out_size, void* d_ws, size_t ws_size,
                              hipStream_t stream) {
    const float* x  = (const float*)d_in[0];
    const int*   ei = (const int*)d_in[1];
    const float* W1 = (const float*)d_in[2];
    const float* b1 = (const float*)d_in[3];
    const float* W2 = (const float*)d_in[4];
    const float* b2 = (const float*)d_in[5];
    const float* Wb = (const float*)d_in[6];
    const float* bb = (const float*)d_in[7];
    float* out = (float*)d_out;

    const int N = N_NODES;
    const int E = in_sizes[1] / 2;
    const int* src = ei;
    const int* dst = ei + E;
    const int GBLK = (N + 127) / 128;        // 391 gemm blocks
    const int SBLK = (E + EPB - 1) / EPB;    // 196 scatter blocks

    // workspace layout
    char* w = (char*)d_ws;
    int*   bcur    = (int*)w;   w += (size_t)512 * 4;
    int*   gbar    = (int*)w;   w += (size_t)32 * 4;
    int*   row_ptr = (int*)w;   w += (size_t)(N + 1) * 4;
    int*   col     = (int*)w;   w += (size_t)E * 4;
    u32*   pair    = (u32*)w;   w += (size_t)NBUCK * CAP * 4;
    float* dinv    = (float*)w; w += (size_t)N * 4;
    float* inv     = (float*)w; w += (size_t)N * 4;
    w = (char*)(((size_t)w + 15) & ~(size_t)15);
    u16* bufA = (u16*)w;        w += (size_t)N * 128 * 2;  // H1; later H2 / Y
    u16* bufB = (u16*)w;        w += (size_t)N * 128 * 2;  // h1
    u16* bufC = (u16*)w;                                   // Z

    u16* H1 = bufA;
    u16* h1 = bufB;
    u16* H2 = bufA;                  // H1 dead after agg1
    u16* Z  = bufC;
    u16* Y  = bufA + (size_t)N * 64; // H2 dead after agg2

    // zero bcur + grid-barrier counters (one memset)
    hipMemsetAsync(bcur, 0, (512 + 32) * 4, stream);

    // gemm1 overlapped with bucket scatter (independent)
    gemm1_scatter<<<GBLK + SBLK, 256, 0, stream>>>(x, W1, H1, N, GBLK,
                                                   src, dst, bcur, pair, E);

    // persistent tail: sort -> agg1 -> gemm2 -> agg2 -> gemmY -> decode
    tail_fused<<<TGRID, 256, 0, stream>>>(pair, bcur, row_ptr, col, dinv, inv,
                                          H1, h1, b1, W2, H2, b2, Z, Wb, Y, bb,
                                          src, dst, out, N, E, gbar);
}

// Round 12
// 239.203 us; speedup vs baseline: 4.3580x; 4.3580x over previous
//
#include <hip/hip_runtime.h>
#include <hip/hip_bf16.h>

// GAE: h1 = relu(gcn(x,W1,b1)); z = gcn(h1,W2,b2); out = sigmoid(dot(Y[src], z[dst]) + bb)
// where Y = z @ Wb[0]  (bilinear refactor).
// PULL aggregation over on-device CSR; gathered node matrices bf16.
// GEMMs: MFMA bf16 split-hi/lo f32 emulation (separate from agg — round-8
// fusion regressed). CSR build: histogram-free fixed-capacity bucket scatter.
// gemm1 + bucket_scatter overlapped in one heterogeneous launch; bucket_sort
// inlines the 391-count prefix (round 10 structure, 240.8 us).
// Round 11 (persistent tail + agent-scope spin barriers) regressed 4.3x:
// spinning acquire loads continuously invalidate per-XCD L2 -> gather kernels
// lost all cache reuse (FETCH 170->320 MB, HBM rate 5.5 TB/s -> 0.39 TB/s).
// Dispatch-boundary ordering flushes L2 once; software grid barriers flush
// it continuously. REVERTED to round-10 exact source.

#define N_NODES 50000
#define BSH 7
#define BSZ 128                             // nodes per bucket
#define NBUCK ((N_NODES + BSZ - 1) / BSZ)   // 391
#define EPB 4096                            // edges per scatter block
#define CAP 3072                            // pair slots per bucket (22 sigma over mean 2048)

typedef unsigned int u32;
typedef unsigned short u16;

typedef __attribute__((ext_vector_type(8))) short bf16x8;
typedef __attribute__((ext_vector_type(4))) float f32x4;
union frag_u { bf16x8 f; u32 u[4]; uint4 v; };

__device__ __forceinline__ float bflo(u32 u) { return __uint_as_float(u << 16); }
__device__ __forceinline__ float bfhi(u32 u) { return __uint_as_float(u & 0xffff0000u); }
__device__ __forceinline__ u32 f2bf(float f) {  // RNE, returns low 16
    u32 b = __float_as_uint(f);
    return (b + 0x7fffu + ((b >> 16) & 1u)) >> 16;
}
__device__ __forceinline__ u32 pack2(float a, float b) { return f2bf(a) | (f2bf(b) << 16); }

// ================= fused: gemm1 (blocks < gblk) | bucket_scatter (rest) =================
// gemm1: H1[n,128](bf16) = x[n,128](f32) @ W1, MFMA split hi/lo (3-term).
// scatter: multisplit edges into fixed-capacity bucket regions of `pair`.
// LDS: union of gemm's Wt_hi/Wt_lo (128*136*2 u16 = 69632 B) and scatter's hist (1564 B).
__global__ __launch_bounds__(256) void gemm1_scatter(
        const float* __restrict__ X, const float* __restrict__ W,
        u16* __restrict__ O, int n_rows, int gblk,
        const int* __restrict__ src, const int* __restrict__ dst,
        int* __restrict__ bcur, u32* __restrict__ pair, int E) {
    constexpr int K = 128, NOUT = 128;
    constexpr int KP = K + 8;
    constexpr int NT = NOUT / 16;
    constexpr int KS = K / 32;
    __shared__ __align__(16) char smem[NOUT * KP * 2 * sizeof(u16)];
    int t = threadIdx.x;

    if ((int)blockIdx.x < gblk) {
        // ---------------- gemm1 path ----------------
        u16* Wt_hi = (u16*)smem;
        u16* Wt_lo = Wt_hi + NOUT * KP;
        for (int i4 = t; i4 < K * NOUT / 4; i4 += 256) {
            int k = (i4 * 4) / NOUT;
            int n0 = (i4 * 4) % NOUT;
            float4 w4 = *(const float4*)&W[(size_t)k * NOUT + n0];
            float wv[4] = {w4.x, w4.y, w4.z, w4.w};
#pragma unroll
            for (int q = 0; q < 4; q++) {
                u32 hi = f2bf(wv[q]);
                u32 lo = f2bf(wv[q] - bflo(hi));
                Wt_hi[(n0 + q) * KP + k] = (u16)hi;
                Wt_lo[(n0 + q) * KP + k] = (u16)lo;
            }
        }
        __syncthreads();

        int wave = t >> 6;
        int lane = t & 63;
        int m16 = lane & 15;
        int quad = lane >> 4;
        int row0 = blockIdx.x * 128 + wave * 32;

        f32x4 acc[2][NT] = {};
        for (int ks = 0; ks < KS; ks++) {
            frag_u a_hi[2], a_lo[2];
#pragma unroll
            for (int mt = 0; mt < 2; mt++) {
                int row = row0 + mt * 16 + m16;
                row = row < n_rows ? row : n_rows - 1;
                const float* Xp = X + (size_t)row * K + ks * 32 + quad * 8;
                float4 x0 = *(const float4*)Xp;
                float4 x1 = *(const float4*)(Xp + 4);
                float xv[8] = {x0.x, x0.y, x0.z, x0.w, x1.x, x1.y, x1.z, x1.w};
#pragma unroll
                for (int p = 0; p < 4; p++) {
                    u32 h0 = f2bf(xv[2 * p]), h1 = f2bf(xv[2 * p + 1]);
                    a_hi[mt].u[p] = h0 | (h1 << 16);
                    a_lo[mt].u[p] = pack2(xv[2 * p] - bflo(h0), xv[2 * p + 1] - bflo(h1));
                }
            }
#pragma unroll
            for (int nt = 0; nt < NT; nt++) {
                int n = nt * 16 + m16;
                frag_u b_hi, b_lo;
                b_hi.v = *(const uint4*)&Wt_hi[n * KP + ks * 32 + quad * 8];
                b_lo.v = *(const uint4*)&Wt_lo[n * KP + ks * 32 + quad * 8];
#pragma unroll
                for (int mt = 0; mt < 2; mt++) {
                    acc[mt][nt] = __builtin_amdgcn_mfma_f32_16x16x32_bf16(a_hi[mt].f, b_hi.f, acc[mt][nt], 0, 0, 0);
                    acc[mt][nt] = __builtin_amdgcn_mfma_f32_16x16x32_bf16(a_hi[mt].f, b_lo.f, acc[mt][nt], 0, 0, 0);
                    acc[mt][nt] = __builtin_amdgcn_mfma_f32_16x16x32_bf16(a_lo[mt].f, b_hi.f, acc[mt][nt], 0, 0, 0);
                }
            }
        }
#pragma unroll
        for (int mt = 0; mt < 2; mt++)
#pragma unroll
            for (int nt = 0; nt < NT; nt++)
#pragma unroll
                for (int r = 0; r < 4; r++) {
                    int row = row0 + mt * 16 + quad * 4 + r;
                    if (row < n_rows)
                        O[(size_t)row * NOUT + nt * 16 + m16] = (u16)f2bf(acc[mt][nt][r]);
                }
    } else {
        // ---------------- scatter path ----------------
        int* hist = (int*)smem;
        for (int i = t; i < NBUCK; i += 256) hist[i] = 0;
        __syncthreads();
        int base = ((int)blockIdx.x - gblk) * EPB;
        int s_[16], d_[16];
#pragma unroll
        for (int it = 0; it < 16; it++) {
            int e = base + it * 256 + t;
            if (e < E) {
                s_[it] = src[e];
                d_[it] = dst[e];
                atomicAdd(&hist[d_[it] >> BSH], 1);
            } else {
                d_[it] = -1;
            }
        }
        __syncthreads();
        for (int b = t; b < NBUCK; b += 256) {
            int c = hist[b];
            hist[b] = c ? (b * CAP + atomicAdd(&bcur[b], c)) : 0;  // absolute chunk base
        }
        __syncthreads();
#pragma unroll
        for (int it = 0; it < 16; it++) {
            if (d_[it] >= 0) {
                int b = d_[it] >> BSH;
                int off = atomicAdd(&hist[b], 1);
                pair[off] = (u32)s_[it] | ((u32)(d_[it] & (BSZ - 1)) << 16);
            }
        }
    }
}

// ---------------- per-bucket: inline prefix over bcur -> row_ptr/dinv/inv, place col ------------
__global__ __launch_bounds__(256) void bucket_sort(const u32* __restrict__ pair,
                                                   const int* __restrict__ bcur,
                                                   int* __restrict__ row_ptr,
                                                   int* __restrict__ col,
                                                   float* __restrict__ dinv,
                                                   float* __restrict__ inv, int n, int E) {
    __shared__ int ssum[256];
    __shared__ int cnt[BSZ];
    __shared__ int scn[BSZ];
    __shared__ int cur[BSZ];
    int t = threadIdx.x;
    int base = blockIdx.x << BSH;
    int nn = min(BSZ, n - base);
    // inline exclusive prefix: b0 = sum(bcur[0..blockIdx.x-1])
    int accp = 0;
    for (int i = t; i < (int)blockIdx.x; i += 256) accp += bcur[i];
    ssum[t] = accp;
    __syncthreads();
    for (int s = 128; s > 0; s >>= 1) {
        if (t < s) ssum[t] += ssum[t + s];
        __syncthreads();
    }
    int b0 = ssum[0];
    int cntE = bcur[blockIdx.x];
    int p0 = blockIdx.x * CAP;
    if (t < BSZ) cnt[t] = 0;
    __syncthreads();
    for (int j = t; j < cntE; j += 256)
        atomicAdd(&cnt[pair[p0 + j] >> 16], 1);
    __syncthreads();
    if (t < BSZ) scn[t] = cnt[t];
    __syncthreads();
    for (int off = 1; off < BSZ; off <<= 1) {
        int a = (t < BSZ && t >= off) ? scn[t - off] : 0;
        __syncthreads();
        if (t < BSZ) scn[t] += a;
        __syncthreads();
    }
    if (t < nn) {
        int excl = b0 + scn[t] - cnt[t];
        row_ptr[base + t] = excl;
        cur[t] = excl;
        float d = (float)cnt[t] + 1.0f;
        dinv[base + t] = rsqrtf(d);
        inv[base + t] = 1.0f / d;
    }
    if (t == 0 && blockIdx.x == NBUCK - 1) row_ptr[n] = E;
    __syncthreads();
    for (int j = t; j < cntE; j += 256) {
        u32 p = pair[p0 + j];
        int ln = (int)(p >> 16);
        int pos = atomicAdd(&cur[ln], 1);
        col[pos] = (int)(p & 0xffffu);
    }
}

// ---------------- MFMA GEMM (layers 2 / Y): O(bf16) = X(bf16) @ W(f32) ----------------
template <int K, int NOUT>
__global__ __launch_bounds__(256) void gemm_mfma_bf(const u16* __restrict__ Xv,
                                                    const float* __restrict__ W,
                                                    u16* __restrict__ O, int n_rows) {
    constexpr int KP = K + 8;
    constexpr int NT = NOUT / 16;
    constexpr int KS = K / 32;
    __shared__ __align__(16) u16 Wt_hi[NOUT * KP];
    __shared__ __align__(16) u16 Wt_lo[NOUT * KP];
    int t = threadIdx.x;
    for (int i4 = t; i4 < K * NOUT / 4; i4 += 256) {
        int k = (i4 * 4) / NOUT;
        int n0 = (i4 * 4) % NOUT;
        float4 w4 = *(const float4*)&W[(size_t)k * NOUT + n0];
        float wv[4] = {w4.x, w4.y, w4.z, w4.w};
#pragma unroll
        for (int q = 0; q < 4; q++) {
            u32 hi = f2bf(wv[q]);
            u32 lo = f2bf(wv[q] - bflo(hi));
            Wt_hi[(n0 + q) * KP + k] = (u16)hi;
            Wt_lo[(n0 + q) * KP + k] = (u16)lo;
        }
    }
    __syncthreads();

    int wave = t >> 6;
    int lane = t & 63;
    int m16 = lane & 15;
    int quad = lane >> 4;
    int row0 = blockIdx.x * 128 + wave * 32;

    f32x4 acc[2][NT] = {};
    for (int ks = 0; ks < KS; ks++) {
        frag_u a_hi[2];
#pragma unroll
        for (int mt = 0; mt < 2; mt++) {
            int row = row0 + mt * 16 + m16;
            row = row < n_rows ? row : n_rows - 1;
            a_hi[mt].v = *(const uint4*)(Xv + (size_t)row * K + ks * 32 + quad * 8);
        }
#pragma unroll
        for (int nt = 0; nt < NT; nt++) {
            int n = nt * 16 + m16;
            frag_u b_hi, b_lo;
            b_hi.v = *(const uint4*)&Wt_hi[n * KP + ks * 32 + quad * 8];
            b_lo.v = *(const uint4*)&Wt_lo[n * KP + ks * 32 + quad * 8];
#pragma unroll
            for (int mt = 0; mt < 2; mt++) {
                acc[mt][nt] = __builtin_amdgcn_mfma_f32_16x16x32_bf16(a_hi[mt].f, b_hi.f, acc[mt][nt], 0, 0, 0);
                acc[mt][nt] = __builtin_amdgcn_mfma_f32_16x16x32_bf16(a_hi[mt].f, b_lo.f, acc[mt][nt], 0, 0, 0);
            }
        }
    }
#pragma unroll
    for (int mt = 0; mt < 2; mt++)
#pragma unroll
        for (int nt = 0; nt < NT; nt++)
#pragma unroll
            for (int r = 0; r < 4; r++) {
                int row = row0 + mt * 16 + quad * 4 + r;
                if (row < n_rows)
                    O[(size_t)row * NOUT + nt * 16 + m16] = (u16)f2bf(acc[mt][nt][r]);
            }
}

// ---------------- pull aggregation + self-loop + bias (+relu), bf16 in/out ----------------
template <int C, bool RELU>
__global__ __launch_bounds__(256) void agg_pull(const u16* __restrict__ H,
                                                const int* __restrict__ row_ptr,
                                                const int* __restrict__ col,
                                                const float* __restrict__ dinv,
                                                const float* __restrict__ inv,
                                                const float* __restrict__ b,
                                                u16* __restrict__ O, int n) {
    constexpr int TPN = C / 8;
    const uint4* Hv = (const uint4*)H;
    int tid = blockIdx.x * 256 + threadIdx.x;
    int node = tid / TPN;
    if (node >= n) return;
    int part = tid % TPN;
    int c8 = part * 8;
    float dn = dinv[node];
    float iv = inv[node];
    float acc[8];
    {
        uint4 h = Hv[(size_t)node * TPN + part];
        acc[0] = bflo(h.x) * iv + b[c8 + 0];
        acc[1] = bfhi(h.x) * iv + b[c8 + 1];
        acc[2] = bflo(h.y) * iv + b[c8 + 2];
        acc[3] = bfhi(h.y) * iv + b[c8 + 3];
        acc[4] = bflo(h.z) * iv + b[c8 + 4];
        acc[5] = bfhi(h.z) * iv + b[c8 + 5];
        acc[6] = bflo(h.w) * iv + b[c8 + 6];
        acc[7] = bfhi(h.w) * iv + b[c8 + 7];
    }
    int j = row_ptr[node];
    int end = row_ptr[node + 1];
    for (; j + 3 < end; j += 4) {
        int s0 = col[j], s1 = col[j + 1], s2 = col[j + 2], s3 = col[j + 3];
        float n0 = dn * dinv[s0], n1 = dn * dinv[s1];
        float n2 = dn * dinv[s2], n3 = dn * dinv[s3];
        uint4 v0 = Hv[(size_t)s0 * TPN + part];
        uint4 v1 = Hv[(size_t)s1 * TPN + part];
        uint4 v2 = Hv[(size_t)s2 * TPN + part];
        uint4 v3 = Hv[(size_t)s3 * TPN + part];
        acc[0] += bflo(v0.x) * n0 + bflo(v1.x) * n1 + bflo(v2.x) * n2 + bflo(v3.x) * n3;
        acc[1] += bfhi(v0.x) * n0 + bfhi(v1.x) * n1 + bfhi(v2.x) * n2 + bfhi(v3.x) * n3;
        acc[2] += bflo(v0.y) * n0 + bflo(v1.y) * n1 + bflo(v2.y) * n2 + bflo(v3.y) * n3;
        acc[3] += bfhi(v0.y) * n0 + bfhi(v1.y) * n1 + bfhi(v2.y) * n2 + bfhi(v3.y) * n3;
        acc[4] += bflo(v0.z) * n0 + bflo(v1.z) * n1 + bflo(v2.z) * n2 + bflo(v3.z) * n3;
        acc[5] += bfhi(v0.z) * n0 + bfhi(v1.z) * n1 + bfhi(v2.z) * n2 + bfhi(v3.z) * n3;
        acc[6] += bflo(v0.w) * n0 + bflo(v1.w) * n1 + bflo(v2.w) * n2 + bflo(v3.w) * n3;
        acc[7] += bfhi(v0.w) * n0 + bfhi(v1.w) * n1 + bfhi(v2.w) * n2 + bfhi(v3.w) * n3;
    }
    for (; j < end; j++) {
        int s = col[j];
        float nm = dn * dinv[s];
        uint4 v = Hv[(size_t)s * TPN + part];
        acc[0] += bflo(v.x) * nm; acc[1] += bfhi(v.x) * nm;
        acc[2] += bflo(v.y) * nm; acc[3] += bfhi(v.y) * nm;
        acc[4] += bflo(v.z) * nm; acc[5] += bfhi(v.z) * nm;
        acc[6] += bflo(v.w) * nm; acc[7] += bfhi(v.w) * nm;
    }
    if (RELU) {
#pragma unroll
        for (int i = 0; i < 8; i++) acc[i] = fmaxf(acc[i], 0.f);
    }
    uint4 o;
    o.x = pack2(acc[0], acc[1]);
    o.y = pack2(acc[2], acc[3]);
    o.z = pack2(acc[4], acc[5]);
    o.w = pack2(acc[6], acc[7]);
    ((uint4*)O)[(size_t)node * TPN + part] = o;
}

// ---------------- decode: out[e] = sigmoid(dot(Y[src], Z[dst]) + bb), bf16 in ----------------
__global__ __launch_bounds__(256) void decode_kernel(const u16* __restrict__ Y,
                                                     const u16* __restrict__ Z,
                                                     const int* __restrict__ src,
                                                     const int* __restrict__ dst,
                                                     const float* __restrict__ bb,
                                                     float* __restrict__ out, int E) {
    const uint4* Yv = (const uint4*)Y;
    const uint4* Zv = (const uint4*)Z;
    int tid = blockIdx.x * 256 + threadIdx.x;
    int e = tid / 8;
    int lane = tid % 8;
    if (e >= E) return;
    int s = src[e], d = dst[e];
    uint4 y = Yv[(size_t)s * 8 + lane];
    uint4 z = Zv[(size_t)d * 8 + lane];
    float p = bflo(y.x) * bflo(z.x) + bfhi(y.x) * bfhi(z.x)
            + bflo(y.y) * bflo(z.y) + bfhi(y.y) * bfhi(z.y)
            + bflo(y.z) * bflo(z.z) + bfhi(y.z) * bfhi(z.z)
            + bflo(y.w) * bflo(z.w) + bfhi(y.w) * bfhi(z.w);
    p += __shfl_down(p, 4, 8);
    p += __shfl_down(p, 2, 8);
    p += __shfl_down(p, 1, 8);
    if (lane == 0) out[e] = 1.0f / (1.0f + expf(-(p + bb[0])));
}

extern "C" void kernel_launch(void* const* d_in, const int* in_sizes, int n_in,
                              void* d_out, int out_size, void* d_ws, size_t ws_size,
                              hipStream_t stream) {
    const float* x  = (const float*)d_in[0];
    const int*   ei = (const int*)d_in[1];
    const float* W1 = (const float*)d_in[2];
    const float* b1 = (const float*)d_in[3];
    const float* W2 = (const float*)d_in[4];
    const float* b2 = (const float*)d_in[5];
    const float* Wb = (const float*)d_in[6];
    const float* bb = (const float*)d_in[7];
    float* out = (float*)d_out;

    const int N = N_NODES;
    const int E = in_sizes[1] / 2;
    const int* src = ei;
    const int* dst = ei + E;
    const int GBLK = (N + 127) / 128;        // 391 gemm blocks
    const int SBLK = (E + EPB - 1) / EPB;    // 196 scatter blocks

    // workspace layout
    char* w = (char*)d_ws;
    int*   bcur    = (int*)w;   w += (size_t)512 * 4;
    int*   row_ptr = (int*)w;   w += (size_t)(N + 1) * 4;
    int*   col     = (int*)w;   w += (size_t)E * 4;
    u32*   pair    = (u32*)w;   w += (size_t)NBUCK * CAP * 4;
    float* dinv    = (float*)w; w += (size_t)N * 4;
    float* inv     = (float*)w; w += (size_t)N * 4;
    w = (char*)(((size_t)w + 15) & ~(size_t)15);
    u16* bufA = (u16*)w;        w += (size_t)N * 128 * 2;  // H1; later H2 / Y
    u16* bufB = (u16*)w;        w += (size_t)N * 128 * 2;  // h1
    u16* bufC = (u16*)w;                                   // Z

    u16* H1 = bufA;
    u16* h1 = bufB;
    u16* H2 = bufA;                  // H1 dead after agg1
    u16* Z  = bufC;
    u16* Y  = bufA + (size_t)N * 64; // H2 dead after agg2

    // CSR build front-end overlapped with layer-1 GEMM (independent work)
    hipMemsetAsync(bcur, 0, 512 * 4, stream);
    gemm1_scatter<<<GBLK + SBLK, 256, 0, stream>>>(x, W1, H1, N, GBLK,
                                                   src, dst, bcur, pair, E);
    bucket_sort<<<NBUCK, 256, 0, stream>>>(pair, bcur, row_ptr, col, dinv, inv, N, E);

    // layer 1 aggregation
    agg_pull<128, true><<<((size_t)N * 16 + 255) / 256, 256, 0, stream>>>(
        H1, row_ptr, col, dinv, inv, b1, h1, N);

    // layer 2
    gemm_mfma_bf<128, 64><<<GBLK, 256, 0, stream>>>(h1, W2, H2, N);
    agg_pull<64, false><<<((size_t)N * 8 + 255) / 256, 256, 0, stream>>>(
        H2, row_ptr, col, dinv, inv, b2, Z, N);

    // decode
    gemm_mfma_bf<64, 64><<<GBLK, 256, 0, stream>>>(Z, Wb, Y, N);
    decode_kernel<<<((size_t)E * 8 + 255) / 256, 256, 0, stream>>>(Y, Z, src, dst, bb, out, E);
}